// Round 13
// baseline (25760.748 us; speedup 1.0000x reference)
//
#include <hip/hip_runtime.h>
#include <stdint.h>

#define BB 128
#define TT 512
#define EE 128
#define HH 256
#define KK 32
#define ASTRD 386          // f64 stride of A-tile rows (384+2): row shift = 4 banks
#define MAGIC 0x13572468

// Workspace: hx f32 [2par][2dir][B][H] @0 (512 KB); cnt @512K; flags @516K;
//            em f64 [B][T][K] @2M (16 MB).
#define OFF_CNT (512ull << 10)
#define OFF_FLG (516ull << 10)
#define OFF_EM  (2ull << 20)

// ---------------------------------------------------------------------------
// k_persist: entire BiLSTM recurrence in one kernel, VALU f64 (no MFMA).
// Grid 256; group g=blk&15 -> (dir=g>>3, tile=g&7); hsl=blk>>4.
//   (group members share blk&7 -> likely same XCD; harmless either way)
// GEMM: R1's signature-proven mapping — tid = tile_t*16+kc; 16 tiles of 8x8
// (2 row-tiles x 8 col-tiles, col c = gate*16+unit); k = 4*kc + 64*i,
// x-phase i in {0,1} (k<128), h-phase i in {2..5}. W f32 swizzled in LDS
// (R1 code verbatim); A-tile staged f64 (exact f32 values).
// Numerics = R10's PASSING lattice: f64 accumulate exact f32 products,
// xg = f32(Sx)+b, g = xg + f32(Sh), f32 cell, f32 h feedback. k-split
// partials reduced by f64 shfl butterfly (fixed association, ~1e-16 class).
// Barrier: per-group LLC atomic counter (R1/R12-proven). x-phase runs
// BEFORE the spin-wait -> barrier latency hidden behind ~1 us of compute.
// LDS ~150 KB (R1 ran at 156 KB) -> 1 block/CU, 256 blocks co-resident.
// ---------------------------------------------------------------------------
__global__ __launch_bounds__(256, 1) void k_persist(
        const int* __restrict__ tok, const float* __restrict__ table,
        const float* __restrict__ Wihf, const float* __restrict__ Whhf,
        const float* __restrict__ bf,
        const float* __restrict__ Wihb, const float* __restrict__ Whhb,
        const float* __restrict__ bb,
        const float* __restrict__ lw,
        float* __restrict__ hx, int* __restrict__ cnt,
        double* __restrict__ em, int* __restrict__ flags) {
    __shared__ __align__(16) double Ah[16 * ASTRD];  // 49.4 KB [x f64 | h f64]
    __shared__ float Wl[64 * 384];                   // 98.3 KB swizzled W
    __shared__ float Gl[16 * 66];                    // 4.2 KB gate values
    __shared__ float Lw[2 * 256];                    // 2 KB lw slice

    const int tid  = threadIdx.x;
    const int blk  = blockIdx.x;
    const int grp  = blk & 15;
    const int dir  = grp >> 3;
    const int tile = grp & 7;
    const int hsl  = blk >> 4;
    const int b0   = tile * 16;
    const int u0   = hsl * 16;
    int* mycnt = cnt + grp * 64;

    if (blk == 0 && tid == 0) flags[8] = MAGIC;      // liveness

    const float* Wih = dir ? Wihb : Wihf;
    const float* Whh = dir ? Whhb : Whhf;
    const float* bia = dir ? bb : bf;

    // ---- one-time: W slice into LDS (R1-proven layout + swizzle) ----
    for (int idx = tid; idx < 64 * 384; idx += 256) {
        int c = idx / 384;
        int k = idx - c * 384;
        int grow = (c >> 4) * HH + u0 + (c & 15);    // c = gate*16+unit
        float v = (k < EE) ? Wih[(size_t)grow * EE + k]
                           : Whh[(size_t)grow * HH + (k - EE)];
        Wl[c * 384 + (k ^ (((c >> 3) & 3) << 2))] = v;
    }
    for (int i = tid; i < 512; i += 256)
        Lw[i] = lw[(size_t)(hsl * 2 + (i >> 8)) * (2 * HH) + dir * HH + (i & 255)];

    // GEMM thread mapping (R1)
    const int kc     = tid & 15;
    const int tile_t = tid >> 4;
    const int r0     = (tile_t >> 3) * 8;
    const int ct     = tile_t & 7;
    const int c0     = ct * 8;
    const int swzc   = (ct & 3) << 2;
    float biasv[8];
#pragma unroll
    for (int m = 0; m < 8; ++m) {
        int c = c0 + m;
        biasv[m] = bia[(c >> 4) * HH + u0 + (c & 15)];
    }

    const int er = tid >> 4, eu = tid & 15;          // cell mapping
    float c_state = 0.f;
    long guard = 0;
    float xg[8][8];

    for (int s = 0; s <= TT; ++s) {
        // ---- stage x(t_s) as f64 (h-independent) ----
        if (s < TT) {
            const int t = dir ? (TT - 1 - s) : s;
            int i = tid;
#pragma unroll
            for (int rep = 0; rep < 2; ++rep, i += 256) {    // 512 float4
                int r = i >> 5, e4 = i & 31;
                int tk = tok[(b0 + r) * TT + t];
                float4 v = make_float4(0.f, 0.f, 0.f, 0.f);
                if (tk != 0) v = ((const float4*)(table + (size_t)tk * EE))[e4];
                double2* dst = (double2*)(Ah + r * ASTRD + e4 * 4);
                dst[0] = make_double2((double)v.x, (double)v.y);
                dst[1] = make_double2((double)v.z, (double)v.w);
            }
        }
        __syncthreads();

        // ---- x-phase GEMM + butterfly + xg (before barrier wait) ----
        if (s < TT) {
            double acc[8][8];
#pragma unroll
            for (int a = 0; a < 8; ++a)
#pragma unroll
                for (int m = 0; m < 8; ++m) acc[a][m] = 0.0;
#pragma unroll
            for (int i = 0; i < 2; ++i) {
                const int k = 4 * kc + 64 * i;
                double av[8][4];
#pragma unroll
                for (int a = 0; a < 8; ++a) {
                    const double2* p = (const double2*)(Ah + (r0 + a) * ASTRD + k);
                    double2 q0 = p[0], q1 = p[1];
                    av[a][0] = q0.x; av[a][1] = q0.y;
                    av[a][2] = q1.x; av[a][3] = q1.y;
                }
#pragma unroll
                for (int m = 0; m < 8; ++m) {
                    float4 wf = *((const float4*)(Wl + (c0 + m) * 384 + (k ^ swzc)));
                    double w0 = wf.x, w1 = wf.y, w2 = wf.z, w3 = wf.w;
#pragma unroll
                    for (int a = 0; a < 8; ++a)
                        acc[a][m] += av[a][0] * w0 + av[a][1] * w1 +
                                     av[a][2] * w2 + av[a][3] * w3;
                }
            }
#pragma unroll
            for (int a = 0; a < 8; ++a)
#pragma unroll
                for (int m = 0; m < 8; ++m) {
                    double v = acc[a][m];
                    v += __shfl_xor(v, 1, 16);
                    v += __shfl_xor(v, 2, 16);
                    v += __shfl_xor(v, 4, 16);
                    v += __shfl_xor(v, 8, 16);
                    xg[a][m] = __fadd_rn((float)v, biasv[m]);  // f32(Sx)+b
                }
        }

        // ---- wait for h(s-1) (signals were sent ~1 us ago; mostly hidden) --
        if (s > 0 && tid == 0) {
            const int target = 16 * s;
            while (__hip_atomic_load(mycnt, __ATOMIC_RELAXED,
                                     __HIP_MEMORY_SCOPE_AGENT) < target) {
                __builtin_amdgcn_s_sleep(2);
                if (++guard > 100000000L) {
                    __hip_atomic_store(&flags[10], s, __ATOMIC_RELAXED,
                                       __HIP_MEMORY_SCOPE_AGENT);
                    break;
                }
            }
            __threadfence();                         // acquire
        }
        __syncthreads();

        // ---- stage h(s-1) as f64 ----
        if (s == 0) {
            for (int i = tid; i < 2048; i += 256) {
                int r = i >> 7, u2 = i & 127;
                *((double2*)(Ah + r * ASTRD + EE + u2 * 2)) = make_double2(0.0, 0.0);
            }
        } else {
            const int rp = (s & 1) ^ 1;
            int i = tid;
#pragma unroll
            for (int rep = 0; rep < 8; ++rep, i += 256) {
                int r = i >> 7, u2 = i & 127;
                const unsigned long long* p = (const unsigned long long*)
                    (hx + ((size_t)((rp * 2 + dir) * BB + b0 + r)) * HH + u2 * 2);
                unsigned long long raw = __hip_atomic_load(
                    p, __ATOMIC_RELAXED, __HIP_MEMORY_SCOPE_AGENT);
                union { unsigned long long u; float f[2]; } cv; cv.u = raw;
                *((double2*)(Ah + r * ASTRD + EE + u2 * 2)) =
                    make_double2((double)cv.f[0], (double)cv.f[1]);
            }
        }
        __syncthreads();

        // ---- emissions partial for step s-1 (R10 association) ----
        if (s >= 1) {
            const int d = tid >> 3, sub = tid & 7;
            const int row = d >> 1, kk = d & 1;
            const int t_em = dir ? (TT - s) : (s - 1);
            double p = 0.0;
#pragma unroll
            for (int j = sub * 32; j < sub * 32 + 32; ++j)
                p += Ah[row * ASTRD + EE + j] * (double)Lw[kk * 256 + j];
            p += __shfl_xor(p, 1, 64);
            p += __shfl_xor(p, 2, 64);
            p += __shfl_xor(p, 4, 64);
            if (sub == 0)
                atomicAdd(em + ((size_t)(b0 + row) * TT + t_em) * KK + hsl * 2 + kk, p);
        }
        if (s == TT) break;

        // ---- h-phase GEMM + butterfly + g -> Gl ----
        {
            double acc[8][8];
#pragma unroll
            for (int a = 0; a < 8; ++a)
#pragma unroll
                for (int m = 0; m < 8; ++m) acc[a][m] = 0.0;
#pragma unroll
            for (int i = 2; i < 6; ++i) {
                const int k = 4 * kc + 64 * i;
                double av[8][4];
#pragma unroll
                for (int a = 0; a < 8; ++a) {
                    const double2* p = (const double2*)(Ah + (r0 + a) * ASTRD + k);
                    double2 q0 = p[0], q1 = p[1];
                    av[a][0] = q0.x; av[a][1] = q0.y;
                    av[a][2] = q1.x; av[a][3] = q1.y;
                }
#pragma unroll
                for (int m = 0; m < 8; ++m) {
                    float4 wf = *((const float4*)(Wl + (c0 + m) * 384 + (k ^ swzc)));
                    double w0 = wf.x, w1 = wf.y, w2 = wf.z, w3 = wf.w;
#pragma unroll
                    for (int a = 0; a < 8; ++a)
                        acc[a][m] += av[a][0] * w0 + av[a][1] * w1 +
                                     av[a][2] * w2 + av[a][3] * w3;
                }
            }
#pragma unroll
            for (int a = 0; a < 8; ++a)
#pragma unroll
                for (int m = 0; m < 8; ++m) {
                    double v = acc[a][m];
                    v += __shfl_xor(v, 1, 16);
                    v += __shfl_xor(v, 2, 16);
                    v += __shfl_xor(v, 4, 16);
                    v += __shfl_xor(v, 8, 16);
                    if (kc == 0)
                        Gl[(r0 + a) * 66 + (c0 + m)] =
                            __fadd_rn(xg[a][m], (float)v);   // xg + f32(Sh)
                }
        }
        __syncthreads();

        // ---- LSTM cell (f32 lattice, R10 ops) + h store ----
        {
            const float gi = Gl[er * 66 +  0 + eu];
            const float gf = Gl[er * 66 + 16 + eu];
            const float gg = Gl[er * 66 + 32 + eu];
            const float go = Gl[er * 66 + 48 + eu];
            const float si = 1.f / (1.f + expf(-gi));
            const float sf = 1.f / (1.f + expf(-gf));
            const float so = 1.f / (1.f + expf(-go));
            const float tg = tanhf(gg);
            const float cnew = __fadd_rn(__fmul_rn(sf, c_state), __fmul_rn(si, tg));
            c_state = cnew;
            const float hval = __fmul_rn(so, tanhf(cnew));
            __hip_atomic_store(
                hx + ((size_t)(((s & 1) * 2 + dir) * BB + b0 + er)) * HH + u0 + eu,
                hval, __ATOMIC_RELAXED, __HIP_MEMORY_SCOPE_AGENT);
        }

        // ---- signal h(s) ready (no spin here; spin is next iter, hidden) --
        __syncthreads();     // drains all waves' h stores (vmcnt(0))
        if (tid == 0) {
            __threadfence();                         // release
            __hip_atomic_fetch_add(mycnt, 1, __ATOMIC_RELAXED,
                                   __HIP_MEMORY_SCOPE_AGENT);
        }
    }
}

// ---------------------------------------------------------------------------
// k_viterbi: f32 DP, reference rounding/order (R10, PASSED verbatim).
// ---------------------------------------------------------------------------
__global__ __launch_bounds__(64) void k_viterbi(const double* __restrict__ em,
                                                const float* __restrict__ lb,
                                                const float* __restrict__ startt,
                                                const float* __restrict__ endt,
                                                const float* __restrict__ trans,
                                                int* __restrict__ out) {
    const int b = blockIdx.x;
    const int lane = threadIdx.x;
    const int j = lane & 31, half = lane >> 5;
    __shared__ float trs[32][33];
    __shared__ unsigned char hist[TT][32];
    __shared__ int tags[TT];

    for (int idx = lane; idx < 1024; idx += 64)
        trs[idx >> 5][idx & 31] = trans[idx];
    __syncthreads();

    const float lbj = lb[j];
    const double* emb = em + (size_t)b * TT * KK;
    float score = __fadd_rn(startt[j], __fadd_rn((float)emb[j], lbj));

    for (int t = 1; t < TT; ++t) {
        const float e_cur = __fadd_rn((float)emb[(size_t)t * KK + j], lbj);
        float best = -3.4e38f; int bi = 0;
#pragma unroll
        for (int ii = 0; ii < 16; ++ii) {
            int i = half * 16 + ii;
            float sc_i = __shfl(score, i, 64);
            float c1 = __fadd_rn(sc_i, trs[i][j]);
            float cand = __fadd_rn(c1, e_cur);
            if (cand > best) { best = cand; bi = i; }    // strict > = first max
        }
        float ob = __shfl_xor(best, 32, 64);
        int obi = __shfl_xor(bi, 32, 64);
        if (ob > best || (ob == best && obi < bi)) { best = ob; bi = obi; }
        score = best;
        if (half == 0) hist[t][j] = (unsigned char)bi;
    }

    score = __fadd_rn(score, endt[j]);
    int bj = j; float bs = score;
#pragma unroll
    for (int off = 16; off >= 1; off >>= 1) {
        float os = __shfl_xor(bs, off, 64);
        int oj = __shfl_xor(bj, off, 64);
        if (os > bs || (os == bs && oj < bj)) { bs = os; bj = oj; }
    }
    __syncthreads();
    if (lane == 0) {
        int cur = bj;
        tags[TT - 1] = cur;
        for (int t = TT - 2; t >= 0; --t) { cur = hist[t + 1][cur]; tags[t] = cur; }
    }
    __syncthreads();
    for (int t2 = lane; t2 < TT; t2 += 64) out[b * TT + t2] = tags[t2];
}

// ---------------------------------------------------------------------------
// k_final: failure decode only (healthy runs untouched).
//   990000      = k_persist never executed (e.g., 150 KB LDS launch failure)
//   850000+s*64 = barrier guard exhausted at step s
// ---------------------------------------------------------------------------
__global__ __launch_bounds__(64) void k_final(const int* __restrict__ flags,
                                              int* __restrict__ outp) {
    if (threadIdx.x != 0) return;
    if (flags[8] != MAGIC)   outp[0] = 990000;
    else if (flags[10] != 0) outp[0] = 850000 + flags[10] * 64;
}

// ---------------------------------------------------------------------------
extern "C" void kernel_launch(void* const* d_in, const int* in_sizes, int n_in,
                              void* d_out, int out_size, void* d_ws, size_t ws_size,
                              hipStream_t stream) {
    const int*   tok   = (const int*)d_in[0];
    const float* table = (const float*)d_in[3];
    const float* Wihf  = (const float*)d_in[4];
    const float* Whhf  = (const float*)d_in[5];
    const float* bf    = (const float*)d_in[6];
    const float* Wihb  = (const float*)d_in[7];
    const float* Whhb  = (const float*)d_in[8];
    const float* bb    = (const float*)d_in[9];
    const float* lw    = (const float*)d_in[10];
    const float* lb    = (const float*)d_in[11];
    const float* st    = (const float*)d_in[12];
    const float* en    = (const float*)d_in[13];
    const float* tr    = (const float*)d_in[14];

    if (ws_size < (19ull << 20)) return;

    char* ws = (char*)d_ws;
    float*  hx    = (float*)ws;
    int*    cnt   = (int*)(ws + OFF_CNT);
    int*    flags = (int*)(ws + OFF_FLG);
    double* em    = (double*)(ws + OFF_EM);

    hipMemsetAsync(cnt, 0, 8192, stream);            // cnt + flags
    hipMemsetAsync(em, 0, (size_t)BB * TT * KK * 8, stream);
    k_persist<<<256, 256, 0, stream>>>(tok, table, Wihf, Whhf, bf,
                                       Wihb, Whhb, bb, lw, hx, cnt, em, flags);
    k_viterbi<<<BB, 64, 0, stream>>>(em, lb, st, en, tr, (int*)d_out);
    k_final  <<<1, 64, 0, stream>>>(flags, (int*)d_out);
}

// Round 14
// 11134.142 us; speedup vs baseline: 2.3137x; 2.3137x over previous
//
#include <hip/hip_runtime.h>
#include <stdint.h>

#define BB 128
#define TT 512
#define EE 128
#define HH 256
#define KK 32
#define ASTRD 386    // f64 stride of A-tile rows (384+2 pad)
#define WSTR  388    // f32 stride of W rows: %32==4 spreads banks, 16B aligned
#define MAGIC 0x13572468

// Workspace: hx f32 [2par][2dir][B][H] @0 (512 KB); cnt @512K; flags @516K;
//            em f64 [B][T][K] @2M (16 MB).
#define OFF_CNT (512ull << 10)
#define OFF_FLG (516ull << 10)
#define OFF_EM  (2ull << 20)

// ---------------------------------------------------------------------------
// k_persist: entire BiLSTM recurrence in one kernel (R13 structure, PASSED),
// with the GEMM remapped for low register pressure (R13 post-mortem: VGPR=256
// -> scratch spills -> 9.6 GB HBM writes, VALUBusy 17%).
// Mapping: lane c = gate-col (64 = 4 gates x 16 units), wave w = batch rows
// 4w..4w+3; each thread: 4 full-K f64 dots, acc[4] = 8 VGPRs only.
//   W: f32 in LDS, stride 388; lane c reads its own row (b128, ~floor).
//   A: [x|h] f64 in LDS; same address across wave = broadcast (conflict-free).
// Numerics unchanged from R13/R10 (PASSED): f64 accumulate exact f32
// products (any fixed order), xg = f32(Sx)+b, g = xg + f32(Sh), f32 cell,
// f32 h lattice. Barrier/fences/h-exchange/em: R13 verbatim.
// LDS: Ah 49.4K + Wl 99.3K + Gl 4.2K + Lw 2K = 155 KB -> 1 block/CU.
// ---------------------------------------------------------------------------
__global__ __launch_bounds__(256, 1) void k_persist(
        const int* __restrict__ tok, const float* __restrict__ table,
        const float* __restrict__ Wihf, const float* __restrict__ Whhf,
        const float* __restrict__ bf,
        const float* __restrict__ Wihb, const float* __restrict__ Whhb,
        const float* __restrict__ bb,
        const float* __restrict__ lw,
        float* __restrict__ hx, int* __restrict__ cnt,
        double* __restrict__ em, int* __restrict__ flags) {
    __shared__ __align__(16) double Ah[16 * ASTRD];
    __shared__ __align__(16) float  Wl[64 * WSTR];
    __shared__ float Gl[16 * 66];
    __shared__ float Lw[2 * 256];

    const int tid  = threadIdx.x;
    const int blk  = blockIdx.x;
    const int grp  = blk & 15;
    const int dir  = grp >> 3;
    const int tile = grp & 7;
    const int hsl  = blk >> 4;
    const int b0   = tile * 16;
    const int u0   = hsl * 16;
    int* mycnt = cnt + grp * 64;

    if (blk == 0 && tid == 0) flags[8] = MAGIC;      // liveness

    const float* Wih = dir ? Wihb : Wihf;
    const float* Whh = dir ? Whhb : Whhf;
    const float* bia = dir ? bb : bf;

    // ---- one-time: W slice into LDS (row c = gate*16+unit, stride 388) ----
    for (int idx = tid; idx < 64 * 384; idx += 256) {
        int c = idx / 384;
        int k = idx - c * 384;
        int grow = (c >> 4) * HH + u0 + (c & 15);
        float v = (k < EE) ? Wih[(size_t)grow * EE + k]
                           : Whh[(size_t)grow * HH + (k - EE)];
        Wl[c * WSTR + k] = v;
    }
    for (int i = tid; i < 512; i += 256)
        Lw[i] = lw[(size_t)(hsl * 2 + (i >> 8)) * (2 * HH) + dir * HH + (i & 255)];

    // GEMM mapping: lane c = gate col, wave w = rows 4w..4w+3
    const int c = tid & 63;
    const int w = tid >> 6;
    const float* WrowL = Wl + c * WSTR;
    const float bias_c = bia[(c >> 4) * HH + u0 + (c & 15)];

    const int er = tid >> 4, eu = tid & 15;          // cell mapping
    float c_state = 0.f;
    long guard = 0;
    float xgv[4];

    for (int s = 0; s <= TT; ++s) {
        // ---- stage x(t_s) as f64 (h-independent) ----
        if (s < TT) {
            const int t = dir ? (TT - 1 - s) : s;
            int i = tid;
#pragma unroll
            for (int rep = 0; rep < 2; ++rep, i += 256) {    // 512 float4
                int r = i >> 5, e4 = i & 31;
                int tk = tok[(b0 + r) * TT + t];
                float4 v = make_float4(0.f, 0.f, 0.f, 0.f);
                if (tk != 0) v = ((const float4*)(table + (size_t)tk * EE))[e4];
                double2* dst = (double2*)(Ah + r * ASTRD + e4 * 4);
                dst[0] = make_double2((double)v.x, (double)v.y);
                dst[1] = make_double2((double)v.z, (double)v.w);
            }
        }
        __syncthreads();

        // ---- x-phase GEMM (before barrier wait; hides inter-block skew) ----
        if (s < TT) {
            double a0 = 0.0, a1 = 0.0, a2 = 0.0, a3 = 0.0;
            const double* A0 = Ah + (4 * w + 0) * ASTRD;
            const double* A1 = Ah + (4 * w + 1) * ASTRD;
            const double* A2 = Ah + (4 * w + 2) * ASTRD;
            const double* A3 = Ah + (4 * w + 3) * ASTRD;
#pragma unroll 4
            for (int k = 0; k < EE; k += 4) {
                float4 wf = *((const float4*)(WrowL + k));
                const double w0 = wf.x, w1 = wf.y, w2 = wf.z, w3 = wf.w;
                double2 q0, q1;
                q0 = *((const double2*)(A0 + k)); q1 = *((const double2*)(A0 + k + 2));
                a0 += q0.x * w0 + q0.y * w1 + q1.x * w2 + q1.y * w3;
                q0 = *((const double2*)(A1 + k)); q1 = *((const double2*)(A1 + k + 2));
                a1 += q0.x * w0 + q0.y * w1 + q1.x * w2 + q1.y * w3;
                q0 = *((const double2*)(A2 + k)); q1 = *((const double2*)(A2 + k + 2));
                a2 += q0.x * w0 + q0.y * w1 + q1.x * w2 + q1.y * w3;
                q0 = *((const double2*)(A3 + k)); q1 = *((const double2*)(A3 + k + 2));
                a3 += q0.x * w0 + q0.y * w1 + q1.x * w2 + q1.y * w3;
            }
            xgv[0] = __fadd_rn((float)a0, bias_c);   // f32(Sx)+b
            xgv[1] = __fadd_rn((float)a1, bias_c);
            xgv[2] = __fadd_rn((float)a2, bias_c);
            xgv[3] = __fadd_rn((float)a3, bias_c);
        }

        // ---- wait for h(s-1) (R13 verbatim) ----
        if (s > 0 && tid == 0) {
            const int target = 16 * s;
            while (__hip_atomic_load(mycnt, __ATOMIC_RELAXED,
                                     __HIP_MEMORY_SCOPE_AGENT) < target) {
                __builtin_amdgcn_s_sleep(2);
                if (++guard > 100000000L) {
                    __hip_atomic_store(&flags[10], s, __ATOMIC_RELAXED,
                                       __HIP_MEMORY_SCOPE_AGENT);
                    break;
                }
            }
            __threadfence();                         // acquire
        }
        __syncthreads();

        // ---- stage h(s-1) as f64 (R13 verbatim) ----
        if (s == 0) {
            for (int i = tid; i < 2048; i += 256) {
                int r = i >> 7, u2 = i & 127;
                *((double2*)(Ah + r * ASTRD + EE + u2 * 2)) = make_double2(0.0, 0.0);
            }
        } else {
            const int rp = (s & 1) ^ 1;
            int i = tid;
#pragma unroll
            for (int rep = 0; rep < 8; ++rep, i += 256) {
                int r = i >> 7, u2 = i & 127;
                const unsigned long long* p = (const unsigned long long*)
                    (hx + ((size_t)((rp * 2 + dir) * BB + b0 + r)) * HH + u2 * 2);
                unsigned long long raw = __hip_atomic_load(
                    p, __ATOMIC_RELAXED, __HIP_MEMORY_SCOPE_AGENT);
                union { unsigned long long u; float f[2]; } cv; cv.u = raw;
                *((double2*)(Ah + r * ASTRD + EE + u2 * 2)) =
                    make_double2((double)cv.f[0], (double)cv.f[1]);
            }
        }
        __syncthreads();

        // ---- emissions partial for step s-1 (R13/R10 verbatim) ----
        if (s >= 1) {
            const int d = tid >> 3, sub = tid & 7;
            const int row = d >> 1, kk = d & 1;
            const int t_em = dir ? (TT - s) : (s - 1);
            double p = 0.0;
#pragma unroll
            for (int j = sub * 32; j < sub * 32 + 32; ++j)
                p += Ah[row * ASTRD + EE + j] * (double)Lw[kk * 256 + j];
            p += __shfl_xor(p, 1, 64);
            p += __shfl_xor(p, 2, 64);
            p += __shfl_xor(p, 4, 64);
            if (sub == 0)
                atomicAdd(em + ((size_t)(b0 + row) * TT + t_em) * KK + hsl * 2 + kk, p);
        }
        if (s == TT) break;

        // ---- h-phase GEMM; g = xg + f32(Sh) -> Gl ----
        {
            double a0 = 0.0, a1 = 0.0, a2 = 0.0, a3 = 0.0;
            const double* A0 = Ah + (4 * w + 0) * ASTRD + EE;
            const double* A1 = Ah + (4 * w + 1) * ASTRD + EE;
            const double* A2 = Ah + (4 * w + 2) * ASTRD + EE;
            const double* A3 = Ah + (4 * w + 3) * ASTRD + EE;
            const float* WhL = WrowL + EE;
#pragma unroll 4
            for (int k = 0; k < HH; k += 4) {
                float4 wf = *((const float4*)(WhL + k));
                const double w0 = wf.x, w1 = wf.y, w2 = wf.z, w3 = wf.w;
                double2 q0, q1;
                q0 = *((const double2*)(A0 + k)); q1 = *((const double2*)(A0 + k + 2));
                a0 += q0.x * w0 + q0.y * w1 + q1.x * w2 + q1.y * w3;
                q0 = *((const double2*)(A1 + k)); q1 = *((const double2*)(A1 + k + 2));
                a1 += q0.x * w0 + q0.y * w1 + q1.x * w2 + q1.y * w3;
                q0 = *((const double2*)(A2 + k)); q1 = *((const double2*)(A2 + k + 2));
                a2 += q0.x * w0 + q0.y * w1 + q1.x * w2 + q1.y * w3;
                q0 = *((const double2*)(A3 + k)); q1 = *((const double2*)(A3 + k + 2));
                a3 += q0.x * w0 + q0.y * w1 + q1.x * w2 + q1.y * w3;
            }
            Gl[(4 * w + 0) * 66 + c] = __fadd_rn(xgv[0], (float)a0);
            Gl[(4 * w + 1) * 66 + c] = __fadd_rn(xgv[1], (float)a1);
            Gl[(4 * w + 2) * 66 + c] = __fadd_rn(xgv[2], (float)a2);
            Gl[(4 * w + 3) * 66 + c] = __fadd_rn(xgv[3], (float)a3);
        }
        __syncthreads();

        // ---- LSTM cell (f32 lattice, R13 verbatim) + h store ----
        {
            const float gi = Gl[er * 66 +  0 + eu];
            const float gf = Gl[er * 66 + 16 + eu];
            const float gg = Gl[er * 66 + 32 + eu];
            const float go = Gl[er * 66 + 48 + eu];
            const float si = 1.f / (1.f + expf(-gi));
            const float sf = 1.f / (1.f + expf(-gf));
            const float so = 1.f / (1.f + expf(-go));
            const float tg = tanhf(gg);
            const float cnew = __fadd_rn(__fmul_rn(sf, c_state), __fmul_rn(si, tg));
            c_state = cnew;
            const float hval = __fmul_rn(so, tanhf(cnew));
            __hip_atomic_store(
                hx + ((size_t)(((s & 1) * 2 + dir) * BB + b0 + er)) * HH + u0 + eu,
                hval, __ATOMIC_RELAXED, __HIP_MEMORY_SCOPE_AGENT);
        }

        // ---- signal h(s) ready (R13 verbatim) ----
        __syncthreads();     // drains all waves' h stores (vmcnt(0))
        if (tid == 0) {
            __threadfence();                         // release
            __hip_atomic_fetch_add(mycnt, 1, __ATOMIC_RELAXED,
                                   __HIP_MEMORY_SCOPE_AGENT);
        }
    }
}

// ---------------------------------------------------------------------------
// k_viterbi: f32 DP, reference rounding/order (R10/R13, PASSED verbatim).
// ---------------------------------------------------------------------------
__global__ __launch_bounds__(64) void k_viterbi(const double* __restrict__ em,
                                                const float* __restrict__ lb,
                                                const float* __restrict__ startt,
                                                const float* __restrict__ endt,
                                                const float* __restrict__ trans,
                                                int* __restrict__ out) {
    const int b = blockIdx.x;
    const int lane = threadIdx.x;
    const int j = lane & 31, half = lane >> 5;
    __shared__ float trs[32][33];
    __shared__ unsigned char hist[TT][32];
    __shared__ int tags[TT];

    for (int idx = lane; idx < 1024; idx += 64)
        trs[idx >> 5][idx & 31] = trans[idx];
    __syncthreads();

    const float lbj = lb[j];
    const double* emb = em + (size_t)b * TT * KK;
    float score = __fadd_rn(startt[j], __fadd_rn((float)emb[j], lbj));

    for (int t = 1; t < TT; ++t) {
        const float e_cur = __fadd_rn((float)emb[(size_t)t * KK + j], lbj);
        float best = -3.4e38f; int bi = 0;
#pragma unroll
        for (int ii = 0; ii < 16; ++ii) {
            int i = half * 16 + ii;
            float sc_i = __shfl(score, i, 64);
            float c1 = __fadd_rn(sc_i, trs[i][j]);
            float cand = __fadd_rn(c1, e_cur);
            if (cand > best) { best = cand; bi = i; }    // strict > = first max
        }
        float ob = __shfl_xor(best, 32, 64);
        int obi = __shfl_xor(bi, 32, 64);
        if (ob > best || (ob == best && obi < bi)) { best = ob; bi = obi; }
        score = best;
        if (half == 0) hist[t][j] = (unsigned char)bi;
    }

    score = __fadd_rn(score, endt[j]);
    int bj = j; float bs = score;
#pragma unroll
    for (int off = 16; off >= 1; off >>= 1) {
        float os = __shfl_xor(bs, off, 64);
        int oj = __shfl_xor(bj, off, 64);
        if (os > bs || (os == bs && oj < bj)) { bs = os; bj = oj; }
    }
    __syncthreads();
    if (lane == 0) {
        int cur = bj;
        tags[TT - 1] = cur;
        for (int t = TT - 2; t >= 0; --t) { cur = hist[t + 1][cur]; tags[t] = cur; }
    }
    __syncthreads();
    for (int t2 = lane; t2 < TT; t2 += 64) out[b * TT + t2] = tags[t2];
}

// ---------------------------------------------------------------------------
// k_final: failure decode only (healthy runs untouched).
// ---------------------------------------------------------------------------
__global__ __launch_bounds__(64) void k_final(const int* __restrict__ flags,
                                              int* __restrict__ outp) {
    if (threadIdx.x != 0) return;
    if (flags[8] != MAGIC)   outp[0] = 990000;
    else if (flags[10] != 0) outp[0] = 850000 + flags[10] * 64;
}

// ---------------------------------------------------------------------------
extern "C" void kernel_launch(void* const* d_in, const int* in_sizes, int n_in,
                              void* d_out, int out_size, void* d_ws, size_t ws_size,
                              hipStream_t stream) {
    const int*   tok   = (const int*)d_in[0];
    const float* table = (const float*)d_in[3];
    const float* Wihf  = (const float*)d_in[4];
    const float* Whhf  = (const float*)d_in[5];
    const float* bf    = (const float*)d_in[6];
    const float* Wihb  = (const float*)d_in[7];
    const float* Whhb  = (const float*)d_in[8];
    const float* bb    = (const float*)d_in[9];
    const float* lw    = (const float*)d_in[10];
    const float* lb    = (const float*)d_in[11];
    const float* st    = (const float*)d_in[12];
    const float* en    = (const float*)d_in[13];
    const float* tr    = (const float*)d_in[14];

    if (ws_size < (19ull << 20)) return;

    char* ws = (char*)d_ws;
    float*  hx    = (float*)ws;
    int*    cnt   = (int*)(ws + OFF_CNT);
    int*    flags = (int*)(ws + OFF_FLG);
    double* em    = (double*)(ws + OFF_EM);

    hipMemsetAsync(cnt, 0, 8192, stream);            // cnt + flags
    hipMemsetAsync(em, 0, (size_t)BB * TT * KK * 8, stream);
    k_persist<<<256, 256, 0, stream>>>(tok, table, Wihf, Whhf, bf,
                                       Wihb, Whhb, bb, lw, hx, cnt, em, flags);
    k_viterbi<<<BB, 64, 0, stream>>>(em, lb, st, en, tr, (int*)d_out);
    k_final  <<<1, 64, 0, stream>>>(flags, (int*)d_out);
}